// Round 1
// baseline (260.762 us; speedup 1.0000x reference)
//
#include <hip/hip_runtime.h>

// Problem constants
#define Bc 8
#define Nc 2048
#define Dc 512
#define Pc 16
#define Hc 32
#define PH 512            // P*H
#define M1 16384          // B*N rows of F
#define NN 4194304        // N*N

#define BM 128
#define BN 128
#define BK 32

typedef __attribute__((ext_vector_type(8))) short bf16x8;
typedef __attribute__((ext_vector_type(4))) float f32x4;

static __device__ __forceinline__ unsigned short f2b(float x) {
    union { float f; unsigned u; } v; v.f = x;
    unsigned r = v.u + 0x7fffu + ((v.u >> 16) & 1u);   // RNE to bf16
    return (unsigned short)(r >> 16);
}

// ---------------------------------------------------------------------------
// prep: context fp32 -> bf16, W fp32 -> bf16, zero rowsum buffer
// ---------------------------------------------------------------------------
__global__ __launch_bounds__(256) void prep_kernel(
    const float* __restrict__ ctx, const float* __restrict__ W,
    unsigned short* __restrict__ Xb, unsigned short* __restrict__ Wb,
    float* __restrict__ rsum) {
    int t = blockIdx.x * 256 + threadIdx.x;
    // context: 8388608 floats = 2097152 float4
    if (t < 2097152) {
        float4 v = ((const float4*)ctx)[t];
        ushort4 o;
        o.x = f2b(v.x); o.y = f2b(v.y); o.z = f2b(v.z); o.w = f2b(v.w);
        ((ushort4*)Xb)[t] = o;
    }
    // W: 262144 floats = 65536 float4
    if (t < 65536) {
        float4 v = ((const float4*)W)[t];
        ushort4 o;
        o.x = f2b(v.x); o.y = f2b(v.y); o.z = f2b(v.z); o.w = f2b(v.w);
        ((ushort4*)Wb)[t] = o;
    }
    // rsum: 16384 floats = 4096 float4
    if (t < 4096) {
        float4 z; z.x = 0.f; z.y = 0.f; z.z = 0.f; z.w = 0.f;
        ((float4*)rsum)[t] = z;
    }
}

// ---------------------------------------------------------------------------
// GEMM1: F = relu(Xb @ Wb^T)   Xb:[16384,512] Wb:[512,512] (both k-contiguous)
// grid: (4, 128), block 256
// ---------------------------------------------------------------------------
__global__ __launch_bounds__(256) void gemm1_relu(
    const unsigned short* __restrict__ Xb, const unsigned short* __restrict__ Wb,
    unsigned short* __restrict__ F) {
    __shared__ unsigned short As[BM * BK];
    __shared__ unsigned short Bs[BN * BK];
    const int tid = threadIdx.x;
    const int lane = tid & 63;
    const int wave = tid >> 6;
    const int wm = wave >> 1, wn = wave & 1;
    const int row0 = blockIdx.y * BM;
    const int col0 = blockIdx.x * BN;

    f32x4 acc[4][4] = {};

    for (int k0 = 0; k0 < Dc; k0 += BK) {
        // stage A,B tiles: 128x32 bf16 each = 512 chunks of 16B each
#pragma unroll
        for (int j = 0; j < 2; ++j) {
            int e = j * 256 + tid;
            int rr = e >> 2, cc = e & 3;
            *(bf16x8*)&As[e * 8] = *(const bf16x8*)&Xb[(size_t)(row0 + rr) * Dc + k0 + cc * 8];
            *(bf16x8*)&Bs[e * 8] = *(const bf16x8*)&Wb[(size_t)(col0 + rr) * Dc + k0 + cc * 8];
        }
        __syncthreads();

        bf16x8 af[4], bfr[4];
#pragma unroll
        for (int i = 0; i < 4; ++i) {
            af[i]  = *(const bf16x8*)&As[(wm * 64 + i * 16 + (lane & 15)) * BK + (lane >> 4) * 8];
            bfr[i] = *(const bf16x8*)&Bs[(wn * 64 + i * 16 + (lane & 15)) * BK + (lane >> 4) * 8];
        }
#pragma unroll
        for (int mi = 0; mi < 4; ++mi)
#pragma unroll
            for (int ni = 0; ni < 4; ++ni)
                acc[mi][ni] = __builtin_amdgcn_mfma_f32_16x16x32_bf16(af[mi], bfr[ni], acc[mi][ni], 0, 0, 0);
        __syncthreads();
    }

    // epilogue: relu + bf16 store.  C/D layout: col=lane&15, row=(lane>>4)*4+reg
#pragma unroll
    for (int mi = 0; mi < 4; ++mi) {
#pragma unroll
        for (int ni = 0; ni < 4; ++ni) {
            int col  = col0 + wn * 64 + ni * 16 + (lane & 15);
            int rowb = row0 + wm * 64 + mi * 16 + ((lane >> 4) << 2);
#pragma unroll
            for (int r = 0; r < 4; ++r) {
                float v = acc[mi][ni][r];
                v = fmaxf(v, 0.0f);
                F[(size_t)(rowb + r) * PH + col] = f2b(v);
            }
        }
    }
}

// ---------------------------------------------------------------------------
// GEMM2: per batch b: S = F[b] @ F[b]^T; out = exp(S/16 - 32); rsum[m] += colsum
// grid: (16, 16, 8), block 256
// ---------------------------------------------------------------------------
__global__ __launch_bounds__(256) void gemm2_exp(
    const unsigned short* __restrict__ F, float* __restrict__ out,
    float* __restrict__ rsum) {
    __shared__ unsigned short As[BM * BK];
    __shared__ unsigned short Bs[BN * BK];
    const int tid = threadIdx.x;
    const int lane = tid & 63;
    const int wave = tid >> 6;
    const int wm = wave >> 1, wn = wave & 1;
    const int b = blockIdx.z;
    const int row0 = blockIdx.y * BM;   // n index
    const int col0 = blockIdx.x * BN;   // m index
    const unsigned short* Fb = F + (size_t)b * Nc * PH;

    f32x4 acc[4][4] = {};

    for (int k0 = 0; k0 < PH; k0 += BK) {
#pragma unroll
        for (int j = 0; j < 2; ++j) {
            int e = j * 256 + tid;
            int rr = e >> 2, cc = e & 3;
            *(bf16x8*)&As[e * 8] = *(const bf16x8*)&Fb[(size_t)(row0 + rr) * PH + k0 + cc * 8];
            *(bf16x8*)&Bs[e * 8] = *(const bf16x8*)&Fb[(size_t)(col0 + rr) * PH + k0 + cc * 8];
        }
        __syncthreads();

        bf16x8 af[4], bfr[4];
#pragma unroll
        for (int i = 0; i < 4; ++i) {
            af[i]  = *(const bf16x8*)&As[(wm * 64 + i * 16 + (lane & 15)) * BK + (lane >> 4) * 8];
            bfr[i] = *(const bf16x8*)&Bs[(wn * 64 + i * 16 + (lane & 15)) * BK + (lane >> 4) * 8];
        }
#pragma unroll
        for (int mi = 0; mi < 4; ++mi)
#pragma unroll
            for (int ni = 0; ni < 4; ++ni)
                acc[mi][ni] = __builtin_amdgcn_mfma_f32_16x16x32_bf16(af[mi], bfr[ni], acc[mi][ni], 0, 0, 0);
        __syncthreads();
    }

    // epilogue: e = exp(acc/16 - 32); store; column sums via shfl + atomics
    float csum[4] = {0.f, 0.f, 0.f, 0.f};
    float* outb = out + (size_t)b * NN;
#pragma unroll
    for (int mi = 0; mi < 4; ++mi) {
#pragma unroll
        for (int ni = 0; ni < 4; ++ni) {
            int col  = col0 + wn * 64 + ni * 16 + (lane & 15);
            int rowb = row0 + wm * 64 + mi * 16 + ((lane >> 4) << 2);
            float s4 = 0.f;
#pragma unroll
            for (int r = 0; r < 4; ++r) {
                float e = __expf(acc[mi][ni][r] * 0.0625f - 32.0f);
                outb[(size_t)(rowb + r) * Nc + col] = e;
                s4 += e;
            }
            csum[ni] += s4;
        }
    }
    // reduce csum across the 4 quads (lanes l, l+16, l+32, l+48 share a column)
#pragma unroll
    for (int ni = 0; ni < 4; ++ni) {
        float s = csum[ni];
        s += __shfl_xor(s, 16);
        s += __shfl_xor(s, 32);
        if ((lane >> 4) == 0) {
            atomicAdd(&rsum[b * Nc + col0 + wn * 64 + ni * 16 + lane], s);
        }
    }
}

// ---------------------------------------------------------------------------
// normalize: out[b,n,m] = out[b,n,m] / rsum[b,m] * mask[b,n] * mask[b,m]
// ---------------------------------------------------------------------------
__global__ __launch_bounds__(256) void norm_kernel(
    float* __restrict__ out, const float* __restrict__ rsum,
    const int* __restrict__ mask) {
    int t = blockIdx.x * 256 + threadIdx.x;   // 8388608 threads, 4 elems each
    int idx4 = t << 2;
    int b  = idx4 >> 22;          // / (N*N)
    int n  = (idx4 >> 11) & 2047; // / N % N
    int m0 = idx4 & 2047;
    float4 v = ((float4*)out)[t];
    const float4 rv = *(const float4*)&rsum[b * Nc + m0];
    float mr = (float)mask[b * Nc + n];
    int4 mc = *(const int4*)&mask[b * Nc + m0];
    v.x = v.x / rv.x * mr * (float)mc.x;
    v.y = v.y / rv.y * mr * (float)mc.y;
    v.z = v.z / rv.z * mr * (float)mc.z;
    v.w = v.w / rv.w * mr * (float)mc.w;
    ((float4*)out)[t] = v;
}

// ---------------------------------------------------------------------------
extern "C" void kernel_launch(void* const* d_in, const int* in_sizes, int n_in,
                              void* d_out, int out_size, void* d_ws, size_t ws_size,
                              hipStream_t stream) {
    const float* ctx  = (const float*)d_in[0];   // [8,2048,512] fp32
    const float* W    = (const float*)d_in[1];   // [16,32,512] fp32
    const int*   mask = (const int*)d_in[2];     // [8,2048] int32
    float* out = (float*)d_out;                  // [8,2048,2048] fp32

    char* ws = (char*)d_ws;
    // layout: Xb bf16 [16384,512] | Wb bf16 [512,512] | F bf16 [16384,512] | rsum f32 [8,2048]
    unsigned short* Xb = (unsigned short*)ws;                              // 16.78 MB
    unsigned short* Wb = (unsigned short*)(ws + 16777216);                 // 0.52 MB
    unsigned short* F  = (unsigned short*)(ws + 16777216 + 524288);        // 16.78 MB
    float* rsum        = (float*)(ws + 16777216 + 524288 + 16777216);      // 64 KB

    prep_kernel<<<8192, 256, 0, stream>>>(ctx, W, Xb, Wb, rsum);
    gemm1_relu<<<dim3(4, 128), 256, 0, stream>>>(Xb, Wb, F);
    gemm2_exp<<<dim3(16, 16, 8), 256, 0, stream>>>(F, out, rsum);
    norm_kernel<<<32768, 256, 0, stream>>>(out, rsum, mask);
}

// Round 2
// 255.462 us; speedup vs baseline: 1.0208x; 1.0208x over previous
//
#include <hip/hip_runtime.h>

// Problem constants
#define Bc 8
#define Nc 2048
#define Dc 512
#define Pc 16
#define Hc 32
#define PH 512            // P*H
#define M1 16384          // B*N rows of F
#define NN 4194304        // N*N

#define BM 128
#define BN 128
#define BK 32

typedef __attribute__((ext_vector_type(8))) short bf16x8;
typedef __attribute__((ext_vector_type(4))) float f32x4;

static __device__ __forceinline__ unsigned short f2b(float x) {
    union { float f; unsigned u; } v; v.f = x;
    unsigned r = v.u + 0x7fffu + ((v.u >> 16) & 1u);   // RNE to bf16
    return (unsigned short)(r >> 16);
}

// async global->LDS DMA, 16 bytes per lane. LDS dest must be
// wave-uniform base + lane*16 — our chunk layout guarantees this.
static __device__ __forceinline__ void load16_lds(const unsigned short* g, unsigned short* l) {
    __builtin_amdgcn_global_load_lds(
        (const __attribute__((address_space(1))) void*)g,
        (__attribute__((address_space(3))) void*)l,
        16, 0, 0);
}

// ---------------------------------------------------------------------------
// prep: context fp32 -> bf16, W fp32 -> bf16, zero rowsum buffer
// ---------------------------------------------------------------------------
__global__ __launch_bounds__(256) void prep_kernel(
    const float* __restrict__ ctx, const float* __restrict__ W,
    unsigned short* __restrict__ Xb, unsigned short* __restrict__ Wb,
    float* __restrict__ rsum) {
    int t = blockIdx.x * 256 + threadIdx.x;
    if (t < 2097152) {
        float4 v = ((const float4*)ctx)[t];
        ushort4 o;
        o.x = f2b(v.x); o.y = f2b(v.y); o.z = f2b(v.z); o.w = f2b(v.w);
        ((ushort4*)Xb)[t] = o;
    }
    if (t < 65536) {
        float4 v = ((const float4*)W)[t];
        ushort4 o;
        o.x = f2b(v.x); o.y = f2b(v.y); o.z = f2b(v.z); o.w = f2b(v.w);
        ((ushort4*)Wb)[t] = o;
    }
    if (t < 4096) {
        float4 z; z.x = 0.f; z.y = 0.f; z.z = 0.f; z.w = 0.f;
        ((float4*)rsum)[t] = z;
    }
}

// ---------------------------------------------------------------------------
// GEMM1: F = relu(Xb @ Wb^T)   Xb:[16384,512] Wb:[512,512] (both k-contiguous)
// grid: (4, 128), block 256
// ---------------------------------------------------------------------------
__global__ __launch_bounds__(256) void gemm1_relu(
    const unsigned short* __restrict__ Xb, const unsigned short* __restrict__ Wb,
    unsigned short* __restrict__ F) {
    __shared__ unsigned short As[BM * BK];
    __shared__ unsigned short Bs[BN * BK];
    const int tid = threadIdx.x;
    const int lane = tid & 63;
    const int wave = tid >> 6;
    const int wm = wave >> 1, wn = wave & 1;
    const int row0 = blockIdx.y * BM;
    const int col0 = blockIdx.x * BN;

    f32x4 acc[4][4] = {};

    for (int k0 = 0; k0 < Dc; k0 += BK) {
        // stage A,B tiles via async DMA: 128x32 bf16 each = 512 x 16B chunks
#pragma unroll
        for (int j = 0; j < 2; ++j) {
            int e = j * 256 + tid;
            int rr = e >> 2, cc = e & 3;
            load16_lds(&Xb[(size_t)(row0 + rr) * Dc + k0 + cc * 8], &As[e * 8]);
            load16_lds(&Wb[(size_t)(col0 + rr) * Dc + k0 + cc * 8], &Bs[e * 8]);
        }
        __syncthreads();   // drains vmcnt for the DMA

        bf16x8 af[4], bfr[4];
#pragma unroll
        for (int i = 0; i < 4; ++i) {
            af[i]  = *(const bf16x8*)&As[(wm * 64 + i * 16 + (lane & 15)) * BK + (lane >> 4) * 8];
            bfr[i] = *(const bf16x8*)&Bs[(wn * 64 + i * 16 + (lane & 15)) * BK + (lane >> 4) * 8];
        }
#pragma unroll
        for (int mi = 0; mi < 4; ++mi)
#pragma unroll
            for (int ni = 0; ni < 4; ++ni)
                acc[mi][ni] = __builtin_amdgcn_mfma_f32_16x16x32_bf16(af[mi], bfr[ni], acc[mi][ni], 0, 0, 0);
        __syncthreads();
    }

    // epilogue: relu + bf16 store.  C/D layout: col=lane&15, row=(lane>>4)*4+reg
#pragma unroll
    for (int mi = 0; mi < 4; ++mi) {
#pragma unroll
        for (int ni = 0; ni < 4; ++ni) {
            int col  = col0 + wn * 64 + ni * 16 + (lane & 15);
            int rowb = row0 + wm * 64 + mi * 16 + ((lane >> 4) << 2);
#pragma unroll
            for (int r = 0; r < 4; ++r) {
                float v = acc[mi][ni][r];
                v = fmaxf(v, 0.0f);
                F[(size_t)(rowb + r) * PH + col] = f2b(v);
            }
        }
    }
}

// ---------------------------------------------------------------------------
// GEMM2: per batch b: S = F[b] @ F[b]^T; out = exp(S/16 - 32); rsum[m] += colsum
// grid: (16, 16, 8), block 256
// ---------------------------------------------------------------------------
__global__ __launch_bounds__(256) void gemm2_exp(
    const unsigned short* __restrict__ F, float* __restrict__ out,
    float* __restrict__ rsum) {
    __shared__ unsigned short As[BM * BK];
    __shared__ unsigned short Bs[BN * BK];
    const int tid = threadIdx.x;
    const int lane = tid & 63;
    const int wave = tid >> 6;
    const int wm = wave >> 1, wn = wave & 1;
    const int b = blockIdx.z;
    const int row0 = blockIdx.y * BM;   // n index
    const int col0 = blockIdx.x * BN;   // m index
    const unsigned short* Fb = F + (size_t)b * Nc * PH;

    f32x4 acc[4][4] = {};

    for (int k0 = 0; k0 < PH; k0 += BK) {
#pragma unroll
        for (int j = 0; j < 2; ++j) {
            int e = j * 256 + tid;
            int rr = e >> 2, cc = e & 3;
            load16_lds(&Fb[(size_t)(row0 + rr) * PH + k0 + cc * 8], &As[e * 8]);
            load16_lds(&Fb[(size_t)(col0 + rr) * PH + k0 + cc * 8], &Bs[e * 8]);
        }
        __syncthreads();

        bf16x8 af[4], bfr[4];
#pragma unroll
        for (int i = 0; i < 4; ++i) {
            af[i]  = *(const bf16x8*)&As[(wm * 64 + i * 16 + (lane & 15)) * BK + (lane >> 4) * 8];
            bfr[i] = *(const bf16x8*)&Bs[(wn * 64 + i * 16 + (lane & 15)) * BK + (lane >> 4) * 8];
        }
#pragma unroll
        for (int mi = 0; mi < 4; ++mi)
#pragma unroll
            for (int ni = 0; ni < 4; ++ni)
                acc[mi][ni] = __builtin_amdgcn_mfma_f32_16x16x32_bf16(af[mi], bfr[ni], acc[mi][ni], 0, 0, 0);
        __syncthreads();
    }

    // epilogue: e = exp(acc/16 - 32); store; column sums via shfl + atomics
    float csum[4] = {0.f, 0.f, 0.f, 0.f};
    float* outb = out + (size_t)b * NN;
#pragma unroll
    for (int mi = 0; mi < 4; ++mi) {
#pragma unroll
        for (int ni = 0; ni < 4; ++ni) {
            int col  = col0 + wn * 64 + ni * 16 + (lane & 15);
            int rowb = row0 + wm * 64 + mi * 16 + ((lane >> 4) << 2);
            float s4 = 0.f;
#pragma unroll
            for (int r = 0; r < 4; ++r) {
                float e = __expf(acc[mi][ni][r] * 0.0625f - 32.0f);
                outb[(size_t)(rowb + r) * Nc + col] = e;
                s4 += e;
            }
            csum[ni] += s4;
        }
    }
    // reduce csum across the 4 quads (lanes l, l+16, l+32, l+48 share a column)
#pragma unroll
    for (int ni = 0; ni < 4; ++ni) {
        float s = csum[ni];
        s += __shfl_xor(s, 16);
        s += __shfl_xor(s, 32);
        if ((lane >> 4) == 0) {
            atomicAdd(&rsum[b * Nc + col0 + wn * 64 + ni * 16 + lane], s);
        }
    }
}

// ---------------------------------------------------------------------------
// normalize: out[b,n,m] = out[b,n,m] / rsum[b,m] * mask[b,n] * mask[b,m]
// ---------------------------------------------------------------------------
__global__ __launch_bounds__(256) void norm_kernel(
    float* __restrict__ out, const float* __restrict__ rsum,
    const int* __restrict__ mask) {
    int t = blockIdx.x * 256 + threadIdx.x;   // 8388608 threads, 4 elems each
    int idx4 = t << 2;
    int b  = idx4 >> 22;          // / (N*N)
    int n  = (idx4 >> 11) & 2047; // / N % N
    int m0 = idx4 & 2047;
    float4 v = ((float4*)out)[t];
    const float4 rv = *(const float4*)&rsum[b * Nc + m0];
    float mr = (float)mask[b * Nc + n];
    int4 mc = *(const int4*)&mask[b * Nc + m0];
    v.x = v.x / rv.x * mr * (float)mc.x;
    v.y = v.y / rv.y * mr * (float)mc.y;
    v.z = v.z / rv.z * mr * (float)mc.z;
    v.w = v.w / rv.w * mr * (float)mc.w;
    ((float4*)out)[t] = v;
}

// ---------------------------------------------------------------------------
extern "C" void kernel_launch(void* const* d_in, const int* in_sizes, int n_in,
                              void* d_out, int out_size, void* d_ws, size_t ws_size,
                              hipStream_t stream) {
    const float* ctx  = (const float*)d_in[0];   // [8,2048,512] fp32
    const float* W    = (const float*)d_in[1];   // [16,32,512] fp32
    const int*   mask = (const int*)d_in[2];     // [8,2048] int32
    float* out = (float*)d_out;                  // [8,2048,2048] fp32

    char* ws = (char*)d_ws;
    // layout: Xb bf16 [16384,512] | Wb bf16 [512,512] | F bf16 [16384,512] | rsum f32 [8,2048]
    unsigned short* Xb = (unsigned short*)ws;                              // 16.78 MB
    unsigned short* Wb = (unsigned short*)(ws + 16777216);                 // 0.52 MB
    unsigned short* F  = (unsigned short*)(ws + 16777216 + 524288);        // 16.78 MB
    float* rsum        = (float*)(ws + 16777216 + 524288 + 16777216);      // 64 KB

    prep_kernel<<<8192, 256, 0, stream>>>(ctx, W, Xb, Wb, rsum);
    gemm1_relu<<<dim3(4, 128), 256, 0, stream>>>(Xb, Wb, F);
    gemm2_exp<<<dim3(16, 16, 8), 256, 0, stream>>>(F, out, rsum);
    norm_kernel<<<32768, 256, 0, stream>>>(out, rsum, mask);
}

// Round 3
// 253.126 us; speedup vs baseline: 1.0302x; 1.0092x over previous
//
#include <hip/hip_runtime.h>

// Problem constants
#define Bc 8
#define Nc 2048
#define Dc 512
#define PH 512            // P*H
#define NN 4194304        // N*N

#define BM 128
#define BN 128
#define BK 32

typedef __attribute__((ext_vector_type(8))) short bf16x8;
typedef __attribute__((ext_vector_type(4))) float f32x4;

static __device__ __forceinline__ unsigned short f2b(float x) {
    union { float f; unsigned u; } v; v.f = x;
    unsigned r = v.u + 0x7fffu + ((v.u >> 16) & 1u);   // RNE to bf16
    return (unsigned short)(r >> 16);
}

// async global->LDS DMA, 16 bytes per lane; LDS dest = wave-uniform base + lane*16
static __device__ __forceinline__ void load16_lds(const unsigned short* g, unsigned short* l) {
    __builtin_amdgcn_global_load_lds(
        (const __attribute__((address_space(1))) void*)g,
        (__attribute__((address_space(3))) void*)l,
        16, 0, 0);
}

// ---------------------------------------------------------------------------
// prep: context fp32 -> bf16, W fp32 -> bf16, zero rsum
// ---------------------------------------------------------------------------
__global__ __launch_bounds__(256) void prep_kernel(
    const float* __restrict__ ctx, const float* __restrict__ W,
    unsigned short* __restrict__ Xb, unsigned short* __restrict__ Wb,
    float* __restrict__ rsum) {
    int t = blockIdx.x * 256 + threadIdx.x;
    if (t < 2097152) {
        float4 v = ((const float4*)ctx)[t];
        ushort4 o;
        o.x = f2b(v.x); o.y = f2b(v.y); o.z = f2b(v.z); o.w = f2b(v.w);
        ((ushort4*)Xb)[t] = o;
    }
    if (t < 65536) {
        float4 v = ((const float4*)W)[t];
        ushort4 o;
        o.x = f2b(v.x); o.y = f2b(v.y); o.z = f2b(v.z); o.w = f2b(v.w);
        ((ushort4*)Wb)[t] = o;
    }
    if (t < 4096) {
        float4 z; z.x = 0.f; z.y = 0.f; z.z = 0.f; z.w = 0.f;
        ((float4*)rsum)[t] = z;
    }
}

// ---------------------------------------------------------------------------
// GEMM1: F = relu(Xb @ Wb^T)   Xb:[16384,512] Wb:[512,512]
// grid: (4, 128), block 256
// ---------------------------------------------------------------------------
__global__ __launch_bounds__(256) void gemm1_relu(
    const unsigned short* __restrict__ Xb, const unsigned short* __restrict__ Wb,
    unsigned short* __restrict__ F) {
    __shared__ unsigned short As[BM * BK];
    __shared__ unsigned short Bs[BN * BK];
    const int tid = threadIdx.x;
    const int lane = tid & 63;
    const int wave = tid >> 6;
    const int wm = wave >> 1, wn = wave & 1;
    const int row0 = blockIdx.y * BM;
    const int col0 = blockIdx.x * BN;

    f32x4 acc[4][4] = {};

    for (int k0 = 0; k0 < Dc; k0 += BK) {
#pragma unroll
        for (int j = 0; j < 2; ++j) {
            int e = j * 256 + tid;
            int rr = e >> 2, cc = e & 3;
            load16_lds(&Xb[(size_t)(row0 + rr) * Dc + k0 + cc * 8], &As[e * 8]);
            load16_lds(&Wb[(size_t)(col0 + rr) * Dc + k0 + cc * 8], &Bs[e * 8]);
        }
        __syncthreads();

        bf16x8 af[4], bfr[4];
#pragma unroll
        for (int i = 0; i < 4; ++i) {
            af[i]  = *(const bf16x8*)&As[(wm * 64 + i * 16 + (lane & 15)) * BK + (lane >> 4) * 8];
            bfr[i] = *(const bf16x8*)&Bs[(wn * 64 + i * 16 + (lane & 15)) * BK + (lane >> 4) * 8];
        }
#pragma unroll
        for (int mi = 0; mi < 4; ++mi)
#pragma unroll
            for (int ni = 0; ni < 4; ++ni)
                acc[mi][ni] = __builtin_amdgcn_mfma_f32_16x16x32_bf16(af[mi], bfr[ni], acc[mi][ni], 0, 0, 0);
        __syncthreads();
    }

#pragma unroll
    for (int mi = 0; mi < 4; ++mi) {
#pragma unroll
        for (int ni = 0; ni < 4; ++ni) {
            int col  = col0 + wn * 64 + ni * 16 + (lane & 15);
            int rowb = row0 + wm * 64 + mi * 16 + ((lane >> 4) << 2);
#pragma unroll
            for (int r = 0; r < 4; ++r) {
                float v = fmaxf(acc[mi][ni][r], 0.0f);
                F[(size_t)(rowb + r) * PH + col] = f2b(v);
            }
        }
    }
}

// ---------------------------------------------------------------------------
// GEMM2a: column sums of exp(S/16-32) using symmetry. Upper-tri tiles only.
// grid: (136, 8), block 256.  No output store.
// ---------------------------------------------------------------------------
__global__ __launch_bounds__(256) void gemm2_rsum(
    const unsigned short* __restrict__ F, float* __restrict__ rsum) {
    __shared__ unsigned short As[BM * BK];
    __shared__ unsigned short Bs[BN * BK];
    const int tid = threadIdx.x;
    const int lane = tid & 63;
    const int wave = tid >> 6;
    const int wm = wave >> 1, wn = wave & 1;
    const int b = blockIdx.y;

    // decode upper-triangular tile index: idx = j*(j+1)/2 + i, i <= j
    int idx = blockIdx.x;
    int j = 0;
    while (((j + 1) * (j + 2) / 2) <= idx) ++j;
    int i = idx - j * (j + 1) / 2;
    const int row0 = i * BM;   // n-tile
    const int col0 = j * BN;   // m-tile
    const unsigned short* Fb = F + (size_t)b * Nc * PH;

    f32x4 acc[4][4] = {};

    for (int k0 = 0; k0 < PH; k0 += BK) {
#pragma unroll
        for (int jj = 0; jj < 2; ++jj) {
            int e = jj * 256 + tid;
            int rr = e >> 2, cc = e & 3;
            load16_lds(&Fb[(size_t)(row0 + rr) * PH + k0 + cc * 8], &As[e * 8]);
            load16_lds(&Fb[(size_t)(col0 + rr) * PH + k0 + cc * 8], &Bs[e * 8]);
        }
        __syncthreads();

        bf16x8 af[4], bfr[4];
#pragma unroll
        for (int q = 0; q < 4; ++q) {
            af[q]  = *(const bf16x8*)&As[(wm * 64 + q * 16 + (lane & 15)) * BK + (lane >> 4) * 8];
            bfr[q] = *(const bf16x8*)&Bs[(wn * 64 + q * 16 + (lane & 15)) * BK + (lane >> 4) * 8];
        }
#pragma unroll
        for (int mi = 0; mi < 4; ++mi)
#pragma unroll
            for (int ni = 0; ni < 4; ++ni)
                acc[mi][ni] = __builtin_amdgcn_mfma_f32_16x16x32_bf16(af[mi], bfr[ni], acc[mi][ni], 0, 0, 0);
        __syncthreads();
    }

    // epilogue: e = exp(acc/16-32); col-sums always; row-sums only off-diag
    float csum[4] = {0.f, 0.f, 0.f, 0.f};   // per ni, reduce over rows
    float rsm[4][4];                         // per (mi, r), reduce over cols
#pragma unroll
    for (int mi = 0; mi < 4; ++mi)
#pragma unroll
        for (int r = 0; r < 4; ++r) rsm[mi][r] = 0.f;

#pragma unroll
    for (int mi = 0; mi < 4; ++mi) {
#pragma unroll
        for (int ni = 0; ni < 4; ++ni) {
#pragma unroll
            for (int r = 0; r < 4; ++r) {
                float e = __expf(acc[mi][ni][r] * 0.0625f - 32.0f);
                csum[ni] += e;
                rsm[mi][r] += e;
            }
        }
    }
    // col-sums: lanes l, l+16, l+32, l+48 share a column
#pragma unroll
    for (int ni = 0; ni < 4; ++ni) {
        float s = csum[ni];
        s += __shfl_xor(s, 16);
        s += __shfl_xor(s, 32);
        if ((lane >> 4) == 0)
            atomicAdd(&rsum[b * Nc + col0 + wn * 64 + ni * 16 + lane], s);
    }
    // row-sums (mirror tile's col-sums): lanes sharing (lane>>4) share a row
    if (i != j) {
#pragma unroll
        for (int mi = 0; mi < 4; ++mi) {
#pragma unroll
            for (int r = 0; r < 4; ++r) {
                float s = rsm[mi][r];
                s += __shfl_xor(s, 1);
                s += __shfl_xor(s, 2);
                s += __shfl_xor(s, 4);
                s += __shfl_xor(s, 8);
                if ((lane & 15) == 0)
                    atomicAdd(&rsum[b * Nc + row0 + wm * 64 + mi * 16 + ((lane >> 4) << 2) + r], s);
            }
        }
    }
}

// ---------------------------------------------------------------------------
// invr[b,m] = mask[b,m] / rsum[b,m]   (folds column mask into the reciprocal)
// ---------------------------------------------------------------------------
__global__ __launch_bounds__(256) void invr_kernel(
    const float* __restrict__ rsum, const int* __restrict__ mask,
    float* __restrict__ invr) {
    int t = blockIdx.x * 256 + threadIdx.x;
    if (t < Bc * Nc) invr[t] = (float)mask[t] / rsum[t];
}

// ---------------------------------------------------------------------------
// GEMM2b: recompute S, write final out = exp(S/16-32) * invr[b,m] * mask[b,n]
// grid: (16, 16, 8), block 256.  Writes out exactly once; no norm pass.
// ---------------------------------------------------------------------------
__global__ __launch_bounds__(256) void gemm2_write(
    const unsigned short* __restrict__ F, const float* __restrict__ invr,
    const int* __restrict__ mask, float* __restrict__ out) {
    __shared__ unsigned short As[BM * BK];
    __shared__ unsigned short Bs[BN * BK];
    const int tid = threadIdx.x;
    const int lane = tid & 63;
    const int wave = tid >> 6;
    const int wm = wave >> 1, wn = wave & 1;
    const int b = blockIdx.z;
    const int row0 = blockIdx.y * BM;   // n
    const int col0 = blockIdx.x * BN;   // m
    const unsigned short* Fb = F + (size_t)b * Nc * PH;

    f32x4 acc[4][4] = {};

    for (int k0 = 0; k0 < PH; k0 += BK) {
#pragma unroll
        for (int jj = 0; jj < 2; ++jj) {
            int e = jj * 256 + tid;
            int rr = e >> 2, cc = e & 3;
            load16_lds(&Fb[(size_t)(row0 + rr) * PH + k0 + cc * 8], &As[e * 8]);
            load16_lds(&Fb[(size_t)(col0 + rr) * PH + k0 + cc * 8], &Bs[e * 8]);
        }
        __syncthreads();

        bf16x8 af[4], bfr[4];
#pragma unroll
        for (int q = 0; q < 4; ++q) {
            af[q]  = *(const bf16x8*)&As[(wm * 64 + q * 16 + (lane & 15)) * BK + (lane >> 4) * 8];
            bfr[q] = *(const bf16x8*)&Bs[(wn * 64 + q * 16 + (lane & 15)) * BK + (lane >> 4) * 8];
        }
#pragma unroll
        for (int mi = 0; mi < 4; ++mi)
#pragma unroll
            for (int ni = 0; ni < 4; ++ni)
                acc[mi][ni] = __builtin_amdgcn_mfma_f32_16x16x32_bf16(af[mi], bfr[ni], acc[mi][ni], 0, 0, 0);
        __syncthreads();
    }

    // epilogue: fused normalize + mask + final store
    float iv[4];
#pragma unroll
    for (int ni = 0; ni < 4; ++ni)
        iv[ni] = invr[b * Nc + col0 + wn * 64 + ni * 16 + (lane & 15)];

    float* outb = out + (size_t)b * NN;
#pragma unroll
    for (int mi = 0; mi < 4; ++mi) {
        int rowb = row0 + wm * 64 + mi * 16 + ((lane >> 4) << 2);
        const int4 mr4 = *(const int4*)&mask[b * Nc + rowb];
        float mr[4] = {(float)mr4.x, (float)mr4.y, (float)mr4.z, (float)mr4.w};
#pragma unroll
        for (int ni = 0; ni < 4; ++ni) {
            int col = col0 + wn * 64 + ni * 16 + (lane & 15);
#pragma unroll
            for (int r = 0; r < 4; ++r) {
                float e = __expf(acc[mi][ni][r] * 0.0625f - 32.0f);
                outb[(size_t)(rowb + r) * Nc + col] = e * iv[ni] * mr[r];
            }
        }
    }
}

// ---------------------------------------------------------------------------
extern "C" void kernel_launch(void* const* d_in, const int* in_sizes, int n_in,
                              void* d_out, int out_size, void* d_ws, size_t ws_size,
                              hipStream_t stream) {
    const float* ctx  = (const float*)d_in[0];   // [8,2048,512] fp32
    const float* W    = (const float*)d_in[1];   // [16,32,512] fp32
    const int*   mask = (const int*)d_in[2];     // [8,2048] int32
    float* out = (float*)d_out;                  // [8,2048,2048] fp32

    char* ws = (char*)d_ws;
    // Xb bf16 [16384,512] | Wb bf16 [512,512] | F bf16 [16384,512] | rsum f32 | invr f32
    unsigned short* Xb = (unsigned short*)ws;
    unsigned short* Wb = (unsigned short*)(ws + 16777216);
    unsigned short* F  = (unsigned short*)(ws + 16777216 + 524288);
    float* rsum        = (float*)(ws + 16777216 + 524288 + 16777216);
    float* invr        = (float*)(ws + 16777216 + 524288 + 16777216 + 65536);

    prep_kernel<<<8192, 256, 0, stream>>>(ctx, W, Xb, Wb, rsum);
    gemm1_relu<<<dim3(4, 128), 256, 0, stream>>>(Xb, Wb, F);
    gemm2_rsum<<<dim3(136, 8), 256, 0, stream>>>(F, rsum);
    invr_kernel<<<64, 256, 0, stream>>>(rsum, mask, invr);
    gemm2_write<<<dim3(16, 16, 8), 256, 0, stream>>>(F, invr, mask, out);
}

// Round 4
// 249.518 us; speedup vs baseline: 1.0451x; 1.0145x over previous
//
#include <hip/hip_runtime.h>

// Problem constants
#define Bc 8
#define Nc 2048
#define Dc 512
#define PH 512            // P*H
#define NN 4194304        // N*N

#define BM 128
#define BN 128
#define BK 32

typedef __attribute__((ext_vector_type(8))) short bf16x8;
typedef __attribute__((ext_vector_type(4))) float f32x4;

static __device__ __forceinline__ unsigned short f2b(float x) {
    union { float f; unsigned u; } v; v.f = x;
    unsigned r = v.u + 0x7fffu + ((v.u >> 16) & 1u);   // RNE to bf16
    return (unsigned short)(r >> 16);
}

// async global->LDS DMA, 16 bytes per lane; LDS dest = wave-uniform base + lane*16
static __device__ __forceinline__ void load16_lds(const unsigned short* g, unsigned short* l) {
    __builtin_amdgcn_global_load_lds(
        (const __attribute__((address_space(1))) void*)g,
        (__attribute__((address_space(3))) void*)l,
        16, 0, 0);
}

// ---------------------------------------------------------------------------
// prep: context fp32 -> bf16, W fp32 -> bf16, zero rsum
// ---------------------------------------------------------------------------
__global__ __launch_bounds__(256) void prep_kernel(
    const float* __restrict__ ctx, const float* __restrict__ W,
    unsigned short* __restrict__ Xb, unsigned short* __restrict__ Wb,
    float* __restrict__ rsum) {
    int t = blockIdx.x * 256 + threadIdx.x;
    if (t < 2097152) {
        float4 v = ((const float4*)ctx)[t];
        ushort4 o;
        o.x = f2b(v.x); o.y = f2b(v.y); o.z = f2b(v.z); o.w = f2b(v.w);
        ((ushort4*)Xb)[t] = o;
    }
    if (t < 65536) {
        float4 v = ((const float4*)W)[t];
        ushort4 o;
        o.x = f2b(v.x); o.y = f2b(v.y); o.z = f2b(v.z); o.w = f2b(v.w);
        ((ushort4*)Wb)[t] = o;
    }
    if (t < 4096) {
        float4 z; z.x = 0.f; z.y = 0.f; z.z = 0.f; z.w = 0.f;
        ((float4*)rsum)[t] = z;
    }
}

// ---------------------------------------------------------------------------
// GEMM1: F = relu(Xb @ Wb^T)   Xb:[16384,512] Wb:[512,512]
// grid: (4, 128), block 256
// ---------------------------------------------------------------------------
__global__ __launch_bounds__(256) void gemm1_relu(
    const unsigned short* __restrict__ Xb, const unsigned short* __restrict__ Wb,
    unsigned short* __restrict__ F) {
    __shared__ unsigned short As[BM * BK];
    __shared__ unsigned short Bs[BN * BK];
    const int tid = threadIdx.x;
    const int lane = tid & 63;
    const int wave = tid >> 6;
    const int wm = wave >> 1, wn = wave & 1;
    const int row0 = blockIdx.y * BM;
    const int col0 = blockIdx.x * BN;

    f32x4 acc[4][4] = {};

    for (int k0 = 0; k0 < Dc; k0 += BK) {
#pragma unroll
        for (int j = 0; j < 2; ++j) {
            int e = j * 256 + tid;
            int rr = e >> 2, cc = e & 3;
            load16_lds(&Xb[(size_t)(row0 + rr) * Dc + k0 + cc * 8], &As[e * 8]);
            load16_lds(&Wb[(size_t)(col0 + rr) * Dc + k0 + cc * 8], &Bs[e * 8]);
        }
        __syncthreads();

        bf16x8 af[4], bfr[4];
#pragma unroll
        for (int i = 0; i < 4; ++i) {
            af[i]  = *(const bf16x8*)&As[(wm * 64 + i * 16 + (lane & 15)) * BK + (lane >> 4) * 8];
            bfr[i] = *(const bf16x8*)&Bs[(wn * 64 + i * 16 + (lane & 15)) * BK + (lane >> 4) * 8];
        }
#pragma unroll
        for (int mi = 0; mi < 4; ++mi)
#pragma unroll
            for (int ni = 0; ni < 4; ++ni)
                acc[mi][ni] = __builtin_amdgcn_mfma_f32_16x16x32_bf16(af[mi], bfr[ni], acc[mi][ni], 0, 0, 0);
        __syncthreads();
    }

#pragma unroll
    for (int mi = 0; mi < 4; ++mi) {
#pragma unroll
        for (int ni = 0; ni < 4; ++ni) {
            int col  = col0 + wn * 64 + ni * 16 + (lane & 15);
            int rowb = row0 + wm * 64 + mi * 16 + ((lane >> 4) << 2);
#pragma unroll
            for (int r = 0; r < 4; ++r) {
                float v = fmaxf(acc[mi][ni][r], 0.0f);
                F[(size_t)(rowb + r) * PH + col] = f2b(v);
            }
        }
    }
}

// ---------------------------------------------------------------------------
// GEMM2a: column sums of exp(S/16-32) using symmetry. Upper-tri tiles only.
// grid: (136, 8), block 256.  No output store.
// ---------------------------------------------------------------------------
__global__ __launch_bounds__(256) void gemm2_rsum(
    const unsigned short* __restrict__ F, float* __restrict__ rsum) {
    __shared__ unsigned short As[BM * BK];
    __shared__ unsigned short Bs[BN * BK];
    const int tid = threadIdx.x;
    const int lane = tid & 63;
    const int wave = tid >> 6;
    const int wm = wave >> 1, wn = wave & 1;
    const int b = blockIdx.y;

    // upper-triangular tile index: idx = j*(j+1)/2 + i, i <= j
    int idx = blockIdx.x;
    int j = 0;
    while (((j + 1) * (j + 2) / 2) <= idx) ++j;
    int i = idx - j * (j + 1) / 2;
    const int row0 = i * BM;
    const int col0 = j * BN;
    const unsigned short* Fb = F + (size_t)b * Nc * PH;

    f32x4 acc[4][4] = {};

    for (int k0 = 0; k0 < PH; k0 += BK) {
#pragma unroll
        for (int jj = 0; jj < 2; ++jj) {
            int e = jj * 256 + tid;
            int rr = e >> 2, cc = e & 3;
            load16_lds(&Fb[(size_t)(row0 + rr) * PH + k0 + cc * 8], &As[e * 8]);
            load16_lds(&Fb[(size_t)(col0 + rr) * PH + k0 + cc * 8], &Bs[e * 8]);
        }
        __syncthreads();

        bf16x8 af[4], bfr[4];
#pragma unroll
        for (int q = 0; q < 4; ++q) {
            af[q]  = *(const bf16x8*)&As[(wm * 64 + q * 16 + (lane & 15)) * BK + (lane >> 4) * 8];
            bfr[q] = *(const bf16x8*)&Bs[(wn * 64 + q * 16 + (lane & 15)) * BK + (lane >> 4) * 8];
        }
#pragma unroll
        for (int mi = 0; mi < 4; ++mi)
#pragma unroll
            for (int ni = 0; ni < 4; ++ni)
                acc[mi][ni] = __builtin_amdgcn_mfma_f32_16x16x32_bf16(af[mi], bfr[ni], acc[mi][ni], 0, 0, 0);
        __syncthreads();
    }

    float csum[4] = {0.f, 0.f, 0.f, 0.f};
    float rsm[4][4];
#pragma unroll
    for (int mi = 0; mi < 4; ++mi)
#pragma unroll
        for (int r = 0; r < 4; ++r) rsm[mi][r] = 0.f;

#pragma unroll
    for (int mi = 0; mi < 4; ++mi) {
#pragma unroll
        for (int ni = 0; ni < 4; ++ni) {
#pragma unroll
            for (int r = 0; r < 4; ++r) {
                float e = __expf(acc[mi][ni][r] * 0.0625f - 32.0f);
                csum[ni] += e;
                rsm[mi][r] += e;
            }
        }
    }
#pragma unroll
    for (int ni = 0; ni < 4; ++ni) {
        float s = csum[ni];
        s += __shfl_xor(s, 16);
        s += __shfl_xor(s, 32);
        if ((lane >> 4) == 0)
            atomicAdd(&rsum[b * Nc + col0 + wn * 64 + ni * 16 + lane], s);
    }
    if (i != j) {
#pragma unroll
        for (int mi = 0; mi < 4; ++mi) {
#pragma unroll
            for (int r = 0; r < 4; ++r) {
                float s = rsm[mi][r];
                s += __shfl_xor(s, 1);
                s += __shfl_xor(s, 2);
                s += __shfl_xor(s, 4);
                s += __shfl_xor(s, 8);
                if ((lane & 15) == 0)
                    atomicAdd(&rsum[b * Nc + row0 + wm * 64 + mi * 16 + ((lane >> 4) << 2) + r], s);
            }
        }
    }
}

// ---------------------------------------------------------------------------
// invr[b,m] = mask[b,m] / rsum[b,m]
// ---------------------------------------------------------------------------
__global__ __launch_bounds__(256) void invr_kernel(
    const float* __restrict__ rsum, const int* __restrict__ mask,
    float* __restrict__ invr) {
    int t = blockIdx.x * 256 + threadIdx.x;
    if (t < Bc * Nc) invr[t] = (float)mask[t] / rsum[t];
}

// ---------------------------------------------------------------------------
// GEMM2b (symmetric): upper-tri tiles only; write original orientation from
// registers and (off-diag) the mirrored tile via LDS transpose.
// grid: (136, 8), block 256.
// ---------------------------------------------------------------------------
__global__ __launch_bounds__(256) void gemm2_write_sym(
    const unsigned short* __restrict__ F, const float* __restrict__ invr,
    const int* __restrict__ mask, float* __restrict__ out) {
    __shared__ unsigned short As[BM * BK];
    __shared__ unsigned short Bs[BN * BK];
    __shared__ float Ts[32 * 132];          // transpose chunk: 32 cols x 128 rows, pad 132
    const int tid = threadIdx.x;
    const int lane = tid & 63;
    const int wave = tid >> 6;
    const int wm = wave >> 1, wn = wave & 1;
    const int l15 = lane & 15, q = lane >> 4;
    const int b = blockIdx.y;

    int idx = blockIdx.x;
    int j = 0;
    while (((j + 1) * (j + 2) / 2) <= idx) ++j;
    int i = idx - j * (j + 1) / 2;
    const int row0 = i * BM;   // n-tile
    const int col0 = j * BN;   // m-tile
    const unsigned short* Fb = F + (size_t)b * Nc * PH;

    f32x4 acc[4][4] = {};

    for (int k0 = 0; k0 < PH; k0 += BK) {
#pragma unroll
        for (int jj = 0; jj < 2; ++jj) {
            int e = jj * 256 + tid;
            int rr = e >> 2, cc = e & 3;
            load16_lds(&Fb[(size_t)(row0 + rr) * PH + k0 + cc * 8], &As[e * 8]);
            load16_lds(&Fb[(size_t)(col0 + rr) * PH + k0 + cc * 8], &Bs[e * 8]);
        }
        __syncthreads();

        bf16x8 af[4], bfr[4];
#pragma unroll
        for (int qq = 0; qq < 4; ++qq) {
            af[qq]  = *(const bf16x8*)&As[(wm * 64 + qq * 16 + l15) * BK + q * 8];
            bfr[qq] = *(const bf16x8*)&Bs[(wn * 64 + qq * 16 + l15) * BK + q * 8];
        }
#pragma unroll
        for (int mi = 0; mi < 4; ++mi)
#pragma unroll
            for (int ni = 0; ni < 4; ++ni)
                acc[mi][ni] = __builtin_amdgcn_mfma_f32_16x16x32_bf16(af[mi], bfr[ni], acc[mi][ni], 0, 0, 0);
        __syncthreads();
    }

    // e = exp(S/16 - 32) in place
#pragma unroll
    for (int mi = 0; mi < 4; ++mi)
#pragma unroll
        for (int ni = 0; ni < 4; ++ni)
#pragma unroll
            for (int r = 0; r < 4; ++r)
                acc[mi][ni][r] = __expf(acc[mi][ni][r] * 0.0625f - 32.0f);

    float* outb = out + (size_t)b * NN;

    // ---- original orientation: out[n=row0+.., m=col0+..] = e * invr[m] * mask[n]
    float iv[4];
#pragma unroll
    for (int ni = 0; ni < 4; ++ni)
        iv[ni] = invr[b * Nc + col0 + wn * 64 + ni * 16 + l15];
#pragma unroll
    for (int mi = 0; mi < 4; ++mi) {
        int rowb = row0 + wm * 64 + mi * 16 + (q << 2);
        const int4 mr4 = *(const int4*)&mask[b * Nc + rowb];
        float mr[4] = {(float)mr4.x, (float)mr4.y, (float)mr4.z, (float)mr4.w};
#pragma unroll
        for (int ni = 0; ni < 4; ++ni) {
            int col = col0 + wn * 64 + ni * 16 + l15;
#pragma unroll
            for (int r = 0; r < 4; ++r)
                outb[(size_t)(rowb + r) * Nc + col] = acc[mi][ni][r] * iv[ni] * mr[r];
        }
    }

    // ---- mirror orientation (off-diag only): out[n=col0+c, m=row0+r] = e[r][c]*invr[row0+r]*mask[col0+c]
    if (i != j) {
#pragma unroll
        for (int ci = 0; ci < 4; ++ci) {
            __syncthreads();   // protect Ts reuse
            if (wn == (ci >> 1)) {
#pragma unroll
                for (int ni2 = 0; ni2 < 2; ++ni2) {
                    int ni = (ci & 1) * 2 + ni2;
#pragma unroll
                    for (int mi = 0; mi < 4; ++mi) {
                        // cols c_local = ni2*16 + l15; rows wm*64+mi*16+q*4 .. +3 (contiguous)
                        *(float4*)&Ts[(ni2 * 16 + l15) * 132 + wm * 64 + mi * 16 + (q << 2)] =
                            *(float4*)&acc[mi][ni];
                    }
                }
            }
            __syncthreads();
            // read transposed: 32 mirror-rows x 128 mirror-cols
            int cl = tid >> 3;          // 0..31  (mirror row within chunk)
            int f0 = tid & 7;
            int nn = col0 + ci * 32 + cl;
            float mrow = (float)mask[b * Nc + nn];
            float* orow = &outb[(size_t)nn * Nc + row0];
#pragma unroll
            for (int g = 0; g < 4; ++g) {
                int f = f0 + g * 8;                       // float4 index along mirror cols
                float4 ev  = *(float4*)&Ts[cl * 132 + 4 * f];
                float4 iv4 = *(const float4*)&invr[b * Nc + row0 + 4 * f];
                float4 o;
                o.x = ev.x * iv4.x * mrow;
                o.y = ev.y * iv4.y * mrow;
                o.z = ev.z * iv4.z * mrow;
                o.w = ev.w * iv4.w * mrow;
                *(float4*)&orow[4 * f] = o;
            }
        }
    }
}

// ---------------------------------------------------------------------------
extern "C" void kernel_launch(void* const* d_in, const int* in_sizes, int n_in,
                              void* d_out, int out_size, void* d_ws, size_t ws_size,
                              hipStream_t stream) {
    const float* ctx  = (const float*)d_in[0];   // [8,2048,512] fp32
    const float* W    = (const float*)d_in[1];   // [16,32,512] fp32
    const int*   mask = (const int*)d_in[2];     // [8,2048] int32
    float* out = (float*)d_out;                  // [8,2048,2048] fp32

    char* ws = (char*)d_ws;
    unsigned short* Xb = (unsigned short*)ws;
    unsigned short* Wb = (unsigned short*)(ws + 16777216);
    unsigned short* F  = (unsigned short*)(ws + 16777216 + 524288);
    float* rsum        = (float*)(ws + 16777216 + 524288 + 16777216);
    float* invr        = (float*)(ws + 16777216 + 524288 + 16777216 + 65536);

    prep_kernel<<<8192, 256, 0, stream>>>(ctx, W, Xb, Wb, rsum);
    gemm1_relu<<<dim3(4, 128), 256, 0, stream>>>(Xb, Wb, F);
    gemm2_rsum<<<dim3(136, 8), 256, 0, stream>>>(F, rsum);
    invr_kernel<<<64, 256, 0, stream>>>(rsum, mask, invr);
    gemm2_write_sym<<<dim3(136, 8), 256, 0, stream>>>(F, invr, mask, out);
}